// Round 7
// baseline (132.451 us; speedup 1.0000x reference)
//
#include <hip/hip_runtime.h>
#include <hip/hip_bf16.h>

#define BATCH 16
#define INP   128
#define OUP   128
#define HH    56
#define WW    56
#define HWSZ  3136
#define HID   768
#define EPSV  1e-5f
#define SCP   198      // k23 stg per-cp stride (dwords): even (b64 align), gcd(198,32)=2 -> 2-way banks

typedef __attribute__((ext_vector_type(8))) short bf16x8;
typedef __attribute__((ext_vector_type(4))) float f32x4;

__device__ __forceinline__ unsigned short f2b(float f) {
    unsigned u = __float_as_uint(f);
    return (unsigned short)((u + 0x7FFFu + ((u >> 16) & 1u)) >> 16);   // RNE
}
__device__ __forceinline__ float blo(unsigned u){ return __uint_as_float(u << 16); }
__device__ __forceinline__ float bhi(unsigned u){ return __uint_as_float(u & 0xFFFF0000u); }
__device__ __forceinline__ unsigned pkbf(float lo, float hi) {
    unsigned r;
    asm("v_cvt_pk_bf16_f32 %0, %1, %2" : "=v"(r) : "v"(lo), "v"(hi));
    return r;
}

// ---------------- prep: fold BN into bf16 weights + mask dilate, once ----------------
__global__ void prep(const float* __restrict__ w1, const float* __restrict__ g1,
                     const float* __restrict__ b1, const float* __restrict__ m1, const float* __restrict__ v1,
                     const float* __restrict__ wdw, const float* __restrict__ g2,
                     const float* __restrict__ b2, const float* __restrict__ m2, const float* __restrict__ v2,
                     const float* __restrict__ w2, const float* __restrict__ g3,
                     const float* __restrict__ b3, const float* __restrict__ m3, const float* __restrict__ v3,
                     const int* __restrict__ mask,
                     unsigned short* __restrict__ w1b, unsigned short* __restrict__ w2b,
                     float* __restrict__ be1o, float* __restrict__ wdsf,
                     float* __restrict__ be2o, float* __restrict__ be3o,
                     float* __restrict__ mdf, float* __restrict__ mff)
{
    int gid = blockIdx.x * blockDim.x + threadIdx.x;
    int stp = gridDim.x * blockDim.x;
    for (int i = gid; i < HID * INP; i += stp) {
        int r = i >> 7;
        float s = g1[r] * rsqrtf(v1[r] + EPSV);
        w1b[i] = f2b(w1[i] * s);
    }
    for (int i = gid; i < OUP * HID; i += stp) {
        int r = i / HID;
        float s = g3[r] * rsqrtf(v3[r] + EPSV);
        w2b[i] = f2b(w2[i] * s);
    }
    for (int i = gid; i < HID; i += stp) {
        float s1 = g1[i] * rsqrtf(v1[i] + EPSV);
        be1o[i] = b1[i] - m1[i] * s1;
        float s2 = g2[i] * rsqrtf(v2[i] + EPSV);
        be2o[i] = b2[i] - m2[i] * s2;
    }
    for (int i = gid; i < HID * 9; i += stp) {          // tap-major [q][c], BN2 scale folded
        int q = i / HID, c = i - q * HID;
        float s2 = g2[c] * rsqrtf(v2[c] + EPSV);
        wdsf[i] = wdw[c * 9 + q] * s2;
    }
    for (int i = gid; i < OUP; i += stp) {
        float s3 = g3[i] * rsqrtf(v3[i] + EPSV);
        be3o[i] = b3[i] - m3[i] * s3;
    }
    for (int i = gid; i < BATCH * HWSZ; i += stp) {     // mf + 3x3 dilated md
        int b = i / HWSZ, p = i - b * HWSZ;
        int y = p / WW, xx = p - y * WW;
        float mf = (float)mask[i];
        float md = 0.f;
        for (int dy = -1; dy <= 1; ++dy)
            for (int dx = -1; dx <= 1; ++dx) {
                int yy = y + dy, xc = xx + dx;
                if (yy >= 0 && yy < HH && xc >= 0 && xc < WW)
                    md = fmaxf(md, (float)mask[b * HWSZ + yy * WW + xc]);
            }
        mff[i] = mf;
        mdf[i] = md;
    }
}

// ---------------- K1: expand GEMM -> h1 (bf16 pair-interleaved [b][c/2][p]) ----------------
__launch_bounds__(256, 4)
__global__ void k1_expand(const float* __restrict__ x,
                          const unsigned short* __restrict__ w1b,
                          const float* __restrict__ be1g,
                          const float* __restrict__ mdf,
                          unsigned* __restrict__ h1p)
{
    __shared__ unsigned short xs[128 * 128];   // 32 KB  bf16 x-tile [px][c] swizzled
    const int t = threadIdx.x, lane = t & 63, wv = t >> 6;
    const int g = lane >> 4, r16 = lane & 15;
    // XCD-chunked swizzle: 2400 = 8 * 300; hb-siblings stay on one XCD (300 % 6 == 0)
    const int pid = blockIdx.x;
    const int l = (pid & 7) * 300 + (pid >> 3);
    const int hb = l % 6;
    const int pb = (l / 6) % 25;
    const int b  = l / 150;
    const int p0 = pb * 128;
    const int whid = wv & 1, wpx = wv >> 1;

    // stage x tile (fp32 -> bf16), coalesced along p
    for (int rep = 0; rep < 16; ++rep) {
        int id = t + rep * 256;
        int px = id & 127, c4 = id >> 7;
        int p = p0 + px;
        ushort4 u; u.x = 0; u.y = 0; u.z = 0; u.w = 0;
        if (p < HWSZ) {
            const float* xp = x + ((size_t)(b * INP + c4 * 4)) * HWSZ + p;
            unsigned lo = pkbf(xp[0], xp[HWSZ]);
            unsigned hi = pkbf(xp[2 * HWSZ], xp[3 * HWSZ]);
            u.x = (unsigned short)lo; u.y = (unsigned short)(lo >> 16);
            u.z = (unsigned short)hi; u.w = (unsigned short)(hi >> 16);
        }
        *(ushort4*)&xs[px * 128 + (((c4 >> 1) ^ (px & 15)) << 3) + ((c4 & 1) << 2)] = u;
    }
    __syncthreads();

    f32x4 acc[4][4];
    #pragma unroll
    for (int mt = 0; mt < 4; ++mt)
        #pragma unroll
        for (int nt = 0; nt < 4; ++nt) {
            acc[mt][nt][0] = 0.f; acc[mt][nt][1] = 0.f;
            acc[mt][nt][2] = 0.f; acc[mt][nt][3] = 0.f;
        }
    const int hbase = hb * 128 + whid * 64;

    #pragma unroll
    for (int ks = 0; ks < 4; ++ks) {
        bf16x8 af[4];
        #pragma unroll
        for (int mt = 0; mt < 4; ++mt)
            af[mt] = *(const bf16x8*)&w1b[(size_t)(hbase + mt * 16 + r16) * INP + ks * 32 + g * 8];
        #pragma unroll
        for (int nt = 0; nt < 4; ++nt) {
            int px = wpx * 64 + nt * 16 + r16;
            bf16x8 bf = *(const bf16x8*)&xs[px * 128 + (((ks * 4 + g) ^ r16) << 3)];
            #pragma unroll
            for (int mt = 0; mt < 4; ++mt)
                acc[mt][nt] = __builtin_amdgcn_mfma_f32_16x16x32_bf16(af[mt], bf, acc[mt][nt], 0, 0, 0);
        }
    }

    // epilogue: BN1 bias + relu6 + md, pack hid-pairs, coalesced dword stores
    #pragma unroll
    for (int nt = 0; nt < 4; ++nt) {
        const int pg = p0 + wpx * 64 + nt * 16;
        if (pg >= HWSZ) continue;              // wave-uniform
        const int p = pg + r16;
        const float md = mdf[b * HWSZ + p];
        #pragma unroll
        for (int mt = 0; mt < 4; ++mt) {
            const float4 be4 = *(const float4*)&be1g[hbase + mt * 16 + g * 4];
            f32x4 a = acc[mt][nt];
            float v0 = fminf(fmaxf(a[0] + be4.x, 0.f), 6.f) * md;
            float v1 = fminf(fmaxf(a[1] + be4.y, 0.f), 6.f) * md;
            float v2 = fminf(fmaxf(a[2] + be4.z, 0.f), 6.f) * md;
            float v3 = fminf(fmaxf(a[3] + be4.w, 0.f), 6.f) * md;
            const int c2 = (hbase >> 1) + mt * 8 + g * 2;
            const size_t ad = (size_t)(b * 384 + c2) * HWSZ + p;
            h1p[ad] = pkbf(v0, v1);
            h1p[ad + HWSZ] = pkbf(v2, v3);
        }
    }
}

// ---------------- K23: depthwise + project per 1-row strip ----------------
__launch_bounds__(256, 4)
__global__ void k23(const unsigned* __restrict__ h1p,
                    const unsigned short* __restrict__ w2b,
                    const float* __restrict__ wdsf,
                    const float* __restrict__ be2g,
                    const float* __restrict__ be3g,
                    const float* __restrict__ mff,
                    const float* __restrict__ x,
                    float* __restrict__ out)
{
    __shared__ unsigned stg[32 * SCP];           // 25344 B  h1 rows [cp][3 rows x 64 dw + pad]
    __shared__ unsigned short h2s[64 * 72];      //  9216 B  h2 [px][c] swizzled (px 56..63 zero)
    __shared__ float mfv_[56];

    const int t = threadIdx.x, lane = t & 63, wv = t >> 6;
    const int g = lane >> 4, r16 = lane & 15;
    // XCD-chunked swizzle: 896 = 8 * 112; consecutive rows (and 2 whole images) per XCD
    const int p = blockIdx.x;
    const int l = (p & 7) * 112 + (p >> 3);
    const int strip = l % 56;                    // output row y0
    const int b = l / 56;
    const int y0 = strip, p0 = strip * 56;

    // ---------------- prologue ----------------
    if (t < 56) mfv_[t] = mff[b * HWSZ + p0 + t];
    {   // zero h2s pad px 56..63
        unsigned* h2d = (unsigned*)h2s;
        for (int i = t; i < 288; i += 256) h2d[2016 + i] = 0;
    }
    for (int i = t; i < 192; i += 256) {         // zero stg edge pads: dw3 (px=-1), dw60 (px=56)
        int cp = i & 31, rs = i >> 5;            // rs 0..5
        int row = rs >> 1, side = rs & 1;
        stg[cp * SCP + row * 64 + (side ? 60 : 3)] = 0;
    }

    uint4 sreg[6];
    auto stageLoad = [&](int ch) {
        #pragma unroll
        for (int rep = 0; rep < 6; ++rep) {
            const int id = t + rep * 256;
            uint4 u; u.x = 0; u.y = 0; u.z = 0; u.w = 0;
            if (id < 1344) {
                const int rr  = (id * 74899) >> 20;          // id/14
                const int px4 = id - rr * 14;
                const int cp  = (rr * 21846) >> 16;          // rr/3
                const int row = rr - 3 * cp;
                const int gy  = y0 - 1 + row;
                if (gy >= 0 && gy < HH)
                    u = *(const uint4*)&h1p[(size_t)(b * 384 + ch * 32 + cp) * HWSZ + gy * WW + px4 * 4];
            }
            sreg[rep] = u;
        }
    };
    auto stageWrite = [&]() {
        #pragma unroll
        for (int rep = 0; rep < 6; ++rep) {
            const int id = t + rep * 256;
            if (id < 1344) {
                const int rr  = (id * 74899) >> 20;
                const int px4 = id - rr * 14;
                const int cp  = (rr * 21846) >> 16;
                const int row = rr - 3 * cp;
                unsigned* s = &stg[cp * SCP + row * 64 + 4 + px4 * 4];
                uint2 a; a.x = sreg[rep].x; a.y = sreg[rep].y;
                uint2 c; c.x = sreg[rep].z; c.y = sreg[rep].w;
                *(uint2*)(s) = a;                 // b64 writes (SCP even -> aligned)
                *(uint2*)(s + 2) = c;
            }
        }
    };

    // dw mapping: lane = channel c (64), wave = px quarter kq
    const int c = lane, kq = wv;
    const int cp_dw = c >> 1;
    const int shl = (c & 1) ? 0 : 16;            // lo half: <<16; hi half: <<0, then mask

    auto phaseDW = [&](int ch) {
        float wt[9];
        #pragma unroll
        for (int q = 0; q < 9; ++q) wt[q] = wdsf[q * HID + ch * 64 + c];
        const float be = be2g[ch * 64 + c];
        float acc[14];
        #pragma unroll
        for (int j = 0; j < 14; ++j) acc[j] = be;
        const unsigned* sg = &stg[cp_dw * SCP];
        #pragma unroll
        for (int dy = 0; dy < 3; ++dy) {
            const unsigned* rp = sg + dy * 64 + 4 + kq * 14;  // dw of px kq*14
            unsigned uw[16];
            uw[0] = rp[-1];
            #pragma unroll
            for (int i = 0; i < 7; ++i) {
                uint2 d = *(const uint2*)(rp + 2 * i);        // even dw -> aligned b64
                uw[1 + 2 * i] = d.x; uw[2 + 2 * i] = d.y;
            }
            uw[15] = rp[14];
            float fl[16];
            #pragma unroll
            for (int i = 0; i < 16; ++i)
                fl[i] = __uint_as_float((uw[i] << shl) & 0xFFFF0000u);
            #pragma unroll
            for (int j = 0; j < 14; ++j)
                acc[j] += fl[j] * wt[dy * 3] + fl[j + 1] * wt[dy * 3 + 1] + fl[j + 2] * wt[dy * 3 + 2];
        }
        #pragma unroll
        for (int j = 0; j < 14; ++j) {
            const int px = kq * 14 + j;
            const float mv = mfv_[px];
            float v = fminf(fmaxf(acc[j], 0.f), 6.f) * mv;
            h2s[px * 72 + (((c >> 3) ^ (px & 7)) << 3) + (c & 7)] = (unsigned short)pkbf(v, v);
        }
    };

    f32x4 pacc[2][4];
    #pragma unroll
    for (int ot = 0; ot < 2; ++ot)
        #pragma unroll
        for (int nt = 0; nt < 4; ++nt) {
            pacc[ot][nt][0] = 0.f; pacc[ot][nt][1] = 0.f;
            pacc[ot][nt][2] = 0.f; pacc[ot][nt][3] = 0.f;
        }

    auto phaseP = [&](int ch) {
        #pragma unroll
        for (int ks = 0; ks < 2; ++ks) {
            bf16x8 pw[2];
            #pragma unroll
            for (int ot = 0; ot < 2; ++ot)
                pw[ot] = *(const bf16x8*)&w2b[(size_t)((wv * 2 + ot) * 16 + r16) * HID + ch * 64 + ks * 32 + g * 8];
            #pragma unroll
            for (int nt = 0; nt < 4; ++nt) {
                const int px = nt * 16 + r16;
                const bf16x8 hb = *(const bf16x8*)&h2s[px * 72 + (((ks * 4 + g) ^ (px & 7)) << 3)];
                #pragma unroll
                for (int ot = 0; ot < 2; ++ot)
                    pacc[ot][nt] = __builtin_amdgcn_mfma_f32_16x16x32_bf16(pw[ot], hb, pacc[ot][nt], 0, 0, 0);
            }
        }
    };

    // ---- main loop: single stg buffer, async reg-stage ----
    stageLoad(0);
    stageWrite();
    __syncthreads();
    for (int ch = 0; ch < 12; ++ch) {
        if (ch + 1 < 12) stageLoad(ch + 1);      // issue global loads early (hide under dw)
        phaseDW(ch);
        __syncthreads();                         // h2s ready; stg free
        if (ch + 1 < 12) stageWrite();           // land next chunk into stg
        phaseP(ch);
        __syncthreads();                         // stg ready; h2s free
    }

    // ---- epilogue: out = x + (proj + be3) * mf ----
    #pragma unroll
    for (int ot = 0; ot < 2; ++ot) {
        const int ob = (wv * 2 + ot) * 16 + g * 4;
        const float4 be4 = *(const float4*)&be3g[ob];
        #pragma unroll
        for (int nt = 0; nt < 4; ++nt) {
            const int px = nt * 16 + r16;
            if (px < 56) {
                const float mv = mfv_[px];
                const size_t base = (size_t)(b * OUP + ob) * HWSZ + p0 + px;
                out[base]            = x[base]            + (pacc[ot][nt][0] + be4.x) * mv;
                out[base + HWSZ]     = x[base + HWSZ]     + (pacc[ot][nt][1] + be4.y) * mv;
                out[base + 2 * HWSZ] = x[base + 2 * HWSZ] + (pacc[ot][nt][2] + be4.z) * mv;
                out[base + 3 * HWSZ] = x[base + 3 * HWSZ] + (pacc[ot][nt][3] + be4.w) * mv;
            }
        }
    }
}

extern "C" void kernel_launch(void* const* d_in, const int* in_sizes, int n_in,
                              void* d_out, int out_size, void* d_ws, size_t ws_size,
                              hipStream_t stream) {
    (void)in_sizes; (void)n_in; (void)out_size; (void)ws_size;
    const float* x   = (const float*)d_in[0];
    const float* w1  = (const float*)d_in[1];
    const float* g1  = (const float*)d_in[2];
    const float* b1  = (const float*)d_in[3];
    const float* m1  = (const float*)d_in[4];
    const float* v1  = (const float*)d_in[5];
    const float* wdw = (const float*)d_in[6];
    const float* g2  = (const float*)d_in[7];
    const float* b2  = (const float*)d_in[8];
    const float* m2  = (const float*)d_in[9];
    const float* v2  = (const float*)d_in[10];
    const float* w2  = (const float*)d_in[11];
    const float* g3  = (const float*)d_in[12];
    const float* b3  = (const float*)d_in[13];
    const float* m3  = (const float*)d_in[14];
    const float* v3  = (const float*)d_in[15];
    const int*  mask = (const int*)d_in[16];
    float* out = (float*)d_out;

    char* ws = (char*)d_ws;
    unsigned short* w1b = (unsigned short*)ws;                 // 196608 B
    unsigned short* w2b = (unsigned short*)(ws + 196608);      // 196608 B
    float* be1o = (float*)(ws + 393216);                       // 3072 B
    float* wdsf = (float*)(ws + 396288);                       // 27648 B  [9][768]
    float* be2o = (float*)(ws + 423936);                       // 3072 B
    float* be3o = (float*)(ws + 427008);                       // 512 B
    float* mdf  = (float*)(ws + 427520);                       // 200704 B
    float* mff  = (float*)(ws + 628224);                       // 200704 B
    unsigned* h1p = (unsigned*)(ws + 828928);                  // 77070336 B (bf16 pairs)

    prep<<<256, 256, 0, stream>>>(w1, g1, b1, m1, v1, wdw, g2, b2, m2, v2,
                                  w2, g3, b3, m3, v3, mask,
                                  w1b, w2b, be1o, wdsf, be2o, be3o, mdf, mff);
    k1_expand<<<dim3(2400), 256, 0, stream>>>(x, w1b, be1o, mdf, h1p);
    k23<<<dim3(896), 256, 0, stream>>>(h1p, w2b, wdsf, be2o, be3o, mff, x, out);
}

// Round 8
// 92.784 us; speedup vs baseline: 1.4275x; 1.4275x over previous
//
#include <hip/hip_runtime.h>
#include <hip/hip_bf16.h>

#define BATCH 16
#define INP   128
#define OUP   128
#define HH    56
#define WW    56
#define HWSZ  3136
#define HID   768
#define EPSV  1e-5f

#define SCPD  62              // k23 stg per-cp stride (dwords): even (b64 align), 2-way banks
#define ROWD  (32 * SCPD)     // 1984 dw per row-block
#define H2STR 72              // h2s elem stride (144B, 16B-aligned)

typedef __attribute__((ext_vector_type(8))) short bf16x8;
typedef __attribute__((ext_vector_type(4))) float f32x4;

__device__ __forceinline__ unsigned short f2b(float f) {
    unsigned u = __float_as_uint(f);
    return (unsigned short)((u + 0x7FFFu + ((u >> 16) & 1u)) >> 16);   // RNE
}
__device__ __forceinline__ unsigned pkbf(float lo, float hi) {
    unsigned r;
    asm("v_cvt_pk_bf16_f32 %0, %1, %2" : "=v"(r) : "v"(lo), "v"(hi));
    return r;
}

// ---------------- prep: fold BN into bf16 weights (fragment-linear) + mask dilate ----------------
__global__ void prep(const float* __restrict__ w1, const float* __restrict__ g1,
                     const float* __restrict__ b1, const float* __restrict__ m1, const float* __restrict__ v1,
                     const float* __restrict__ wdw, const float* __restrict__ g2,
                     const float* __restrict__ b2, const float* __restrict__ m2, const float* __restrict__ v2,
                     const float* __restrict__ w2, const float* __restrict__ g3,
                     const float* __restrict__ b3, const float* __restrict__ m3, const float* __restrict__ v3,
                     const int* __restrict__ mask,
                     unsigned short* __restrict__ w1f, unsigned short* __restrict__ w2f,
                     float* __restrict__ be1o, float* __restrict__ wdsf,
                     float* __restrict__ be2o, float* __restrict__ be3o,
                     float* __restrict__ mdf, float* __restrict__ mff)
{
    int gid = blockIdx.x * blockDim.x + threadIdx.x;
    int stp = gridDim.x * blockDim.x;
    // w1 fragment-linear: [ht 48][ks 4][g 4][r16 16][e 8]
    for (int i = gid; i < HID * INP; i += stp) {
        int r = i >> 7, k = i & 127;
        float s = g1[r] * rsqrtf(v1[r] + EPSV);
        int ht = r >> 4, r16 = r & 15, ks = k >> 5, g = (k >> 3) & 3, e = k & 7;
        w1f[((((ht * 4 + ks) * 4 + g) * 16 + r16) << 3) + e] = f2b(w1[i] * s);
    }
    // w2 fragment-linear: [ot 8][ch 12][ks 2][lane 64][e 8]
    for (int i = gid; i < OUP * HID; i += stp) {
        int r = i / HID, k = i - r * HID;
        float s = g3[r] * rsqrtf(v3[r] + EPSV);
        int ot = r >> 4, r16 = r & 15, ch = k >> 6, ks = (k >> 5) & 1, g = (k >> 3) & 3, e = k & 7;
        int lane = g * 16 + r16;
        w2f[((((ot * 12 + ch) * 2 + ks) * 64 + lane) << 3) + e] = f2b(w2[i] * s);
    }
    for (int i = gid; i < HID; i += stp) {
        float s1 = g1[i] * rsqrtf(v1[i] + EPSV);
        be1o[i] = b1[i] - m1[i] * s1;
        float s2 = g2[i] * rsqrtf(v2[i] + EPSV);
        be2o[i] = b2[i] - m2[i] * s2;
    }
    for (int i = gid; i < HID * 9; i += stp) {          // tap-major [q][c], BN2 scale folded
        int q = i / HID, c = i - q * HID;
        float s2 = g2[c] * rsqrtf(v2[c] + EPSV);
        wdsf[i] = wdw[c * 9 + q] * s2;
    }
    for (int i = gid; i < OUP; i += stp) {
        float s3 = g3[i] * rsqrtf(v3[i] + EPSV);
        be3o[i] = b3[i] - m3[i] * s3;
    }
    for (int i = gid; i < BATCH * HWSZ; i += stp) {     // mf + 3x3 dilated md
        int b = i / HWSZ, p = i - b * HWSZ;
        int y = p / WW, xx = p - y * WW;
        float mf = (float)mask[i];
        float md = 0.f;
        for (int dy = -1; dy <= 1; ++dy)
            for (int dx = -1; dx <= 1; ++dx) {
                int yy = y + dy, xc = xx + dx;
                if (yy >= 0 && yy < HH && xc >= 0 && xc < WW)
                    md = fmaxf(md, (float)mask[b * HWSZ + yy * WW + xc]);
            }
        mff[i] = mf;
        mdf[i] = md;
    }
}

// ---------------- K1: expand GEMM -> h1 (bf16 pair-interleaved [b][c/2][p]) ----------------
// block: 256 hid x 128 px, 512 thr; x staged ONCE per block; single barrier.
__launch_bounds__(512, 4)
__global__ void k1_expand(const float* __restrict__ x,
                          const unsigned short* __restrict__ w1f,
                          const float* __restrict__ be1g,
                          const float* __restrict__ mdf,
                          unsigned* __restrict__ h1p)
{
    __shared__ unsigned short xs[128 * 128];   // 32 KB  bf16 x-tile [px][c] swizzled
    const int t = threadIdx.x, lane = t & 63, wv = t >> 6;
    const int g = lane >> 4, r16 = lane & 15;
    // XCD swizzle: 1200 = 8*150; hb-siblings adjacent -> share x tile in L2
    const int pid = blockIdx.x;
    const int l = (pid & 7) * 150 + (pid >> 3);
    const int hb = l % 3;
    const int pb = (l / 3) % 25;
    const int b  = l / 75;
    const int p0 = pb * 128;
    const int whid = wv & 3;       // 4 hid quarters of 64
    const int wpx  = wv >> 2;      // 2 px halves of 64

    // stage x tile (fp32 -> bf16), coalesced along p
    for (int rep = 0; rep < 8; ++rep) {
        int id = t + rep * 512;
        int px = id & 127, c4 = id >> 7;
        int p = p0 + px;
        ushort4 u; u.x = 0; u.y = 0; u.z = 0; u.w = 0;
        if (p < HWSZ) {
            const float* xp = x + ((size_t)(b * INP + c4 * 4)) * HWSZ + p;
            unsigned lo = pkbf(xp[0], xp[HWSZ]);
            unsigned hi = pkbf(xp[2 * HWSZ], xp[3 * HWSZ]);
            u.x = (unsigned short)lo; u.y = (unsigned short)(lo >> 16);
            u.z = (unsigned short)hi; u.w = (unsigned short)(hi >> 16);
        }
        *(ushort4*)&xs[px * 128 + (((c4 >> 1) ^ (px & 15)) << 3) + ((c4 & 1) << 2)] = u;
    }
    __syncthreads();

    f32x4 acc[4][4];
    #pragma unroll
    for (int mt = 0; mt < 4; ++mt)
        #pragma unroll
        for (int nt = 0; nt < 4; ++nt) {
            acc[mt][nt][0] = 0.f; acc[mt][nt][1] = 0.f;
            acc[mt][nt][2] = 0.f; acc[mt][nt][3] = 0.f;
        }
    const int hbase = hb * 256 + whid * 64;
    const int htb = hbase >> 4;    // first 16-row tile index

    #pragma unroll
    for (int ks = 0; ks < 4; ++ks) {
        bf16x8 af[4];
        #pragma unroll
        for (int mt = 0; mt < 4; ++mt)     // coalesced 1KB wave-load
            af[mt] = *(const bf16x8*)&w1f[((((htb + mt) * 4 + ks) * 64) + lane) << 3];
        #pragma unroll
        for (int nt = 0; nt < 4; ++nt) {
            int px = wpx * 64 + nt * 16 + r16;
            bf16x8 bf = *(const bf16x8*)&xs[px * 128 + (((ks * 4 + g) ^ r16) << 3)];
            #pragma unroll
            for (int mt = 0; mt < 4; ++mt)
                acc[mt][nt] = __builtin_amdgcn_mfma_f32_16x16x32_bf16(af[mt], bf, acc[mt][nt], 0, 0, 0);
        }
    }

    // epilogue: BN1 bias + relu6 + md, pack hid-pairs, coalesced dword stores
    #pragma unroll
    for (int nt = 0; nt < 4; ++nt) {
        const int pg = p0 + wpx * 64 + nt * 16;
        if (pg >= HWSZ) continue;              // wave-uniform (tile is 16-aligned vs 3136)
        const int p = pg + r16;
        const float md = mdf[b * HWSZ + p];
        #pragma unroll
        for (int mt = 0; mt < 4; ++mt) {
            const float4 be4 = *(const float4*)&be1g[hbase + mt * 16 + g * 4];
            f32x4 a = acc[mt][nt];
            float v0 = fminf(fmaxf(a[0] + be4.x, 0.f), 6.f) * md;
            float v1 = fminf(fmaxf(a[1] + be4.y, 0.f), 6.f) * md;
            float v2 = fminf(fmaxf(a[2] + be4.z, 0.f), 6.f) * md;
            float v3 = fminf(fmaxf(a[3] + be4.w, 0.f), 6.f) * md;
            const int c2 = (hbase >> 1) + mt * 8 + g * 2;
            const size_t ad = (size_t)(b * 384 + c2) * HWSZ + p;
            h1p[ad] = pkbf(v0, v1);
            h1p[ad + HWSZ] = pkbf(v2, v3);
        }
    }
}

// ---------------- K23: depthwise + project per 2-row strip, 512 thr ----------------
__launch_bounds__(512, 4)
__global__ void k23(const unsigned* __restrict__ h1p,
                    const unsigned short* __restrict__ w2f,
                    const float* __restrict__ wdsf,
                    const float* __restrict__ be2g,
                    const float* __restrict__ be3g,
                    const float* __restrict__ mff,
                    const float* __restrict__ x,
                    float* __restrict__ out)
{
    __shared__ unsigned stg[2 * 4 * ROWD];       // 63488 B  h1 rows [buf][row 4][cp 32][62 dw]
    __shared__ unsigned short h2s[112 * H2STR];  // 16128 B  h2 [px][c] swizzled
    __shared__ float mfv_[112];
    // total 80064 B -> 2 blocks/CU

    const int t = threadIdx.x, lane = t & 63, wv = t >> 6;
    const int g = lane >> 4, r16 = lane & 15;
    // XCD swizzle: 448 = 8*56; adjacent strips per XCD (halo L2 sharing)
    const int pid = blockIdx.x;
    const int l = (pid & 7) * 56 + (pid >> 3);
    const int strip = l % 28, b = l / 28;
    const int y0 = strip * 2, p0 = strip * 112;

    // ---------------- prologue ----------------
    if (t < 112) mfv_[t] = mff[b * HWSZ + p0 + t];
    {   // zero stg edge dwords (px=-1 at off 1, px=56 at off 58): 2buf x 4row x 32cp x 2 = 512
        int cp = t & 31, rs = (t >> 5) & 7, side = t >> 8;
        stg[rs * ROWD + cp * SCPD + (side ? 58 : 1)] = 0;
    }

    auto stage = [&](int ch) {
        #pragma unroll
        for (int rep = 0; rep < 4; ++rep) {
            const int id = t + rep * 512;
            if (id < 1792) {                                  // cp32 x row4 x px4_14
                const int rr  = (id * 4682) >> 16;            // id/14
                const int px4 = id - rr * 14;
                const int row = rr & 3, cp = rr >> 2;
                const int gy = y0 - 1 + row;
                uint4 u; u.x = 0; u.y = 0; u.z = 0; u.w = 0;
                if (gy >= 0 && gy < HH)
                    u = *(const uint4*)&h1p[(size_t)(b * 384 + ch * 32 + cp) * HWSZ + gy * WW + px4 * 4];
                unsigned* s = &stg[((ch & 1) * 4 + row) * ROWD + cp * SCPD + 2 + px4 * 4];
                uint2 a; a.x = u.x; a.y = u.y;
                uint2 c; c.x = u.z; c.y = u.w;
                *(uint2*)(s) = a;
                *(uint2*)(s + 2) = c;
            }
        }
    };

    // dw mapping: thread -> (c 64, row2 2, q 4); 14 px each
    const int c = lane, row2 = (t >> 6) & 1, q = t >> 7;
    const int cp_dw = c >> 1;
    const int shl = (c & 1) ? 0 : 16;

    auto phaseDW = [&](int ch) {
        float wt[9];
        #pragma unroll
        for (int q9 = 0; q9 < 9; ++q9) wt[q9] = wdsf[q9 * HID + ch * 64 + c];
        const float be = be2g[ch * 64 + c];
        float acc[14];
        #pragma unroll
        for (int j = 0; j < 14; ++j) acc[j] = be;
        const unsigned* sb = &stg[(ch & 1) * 4 * ROWD + cp_dw * SCPD + 2 + q * 14];
        #pragma unroll
        for (int dy = 0; dy < 3; ++dy) {
            const unsigned* rp = sb + (row2 + dy) * ROWD;
            unsigned uw[16];
            uw[0] = rp[-1];
            #pragma unroll
            for (int i = 0; i < 7; ++i) {
                uint2 d = *(const uint2*)(rp + 2 * i);        // even base -> aligned b64
                uw[1 + 2 * i] = d.x; uw[2 + 2 * i] = d.y;
            }
            uw[15] = rp[14];
            float fl[16];
            #pragma unroll
            for (int i = 0; i < 16; ++i)
                fl[i] = __uint_as_float((uw[i] << shl) & 0xFFFF0000u);
            #pragma unroll
            for (int j = 0; j < 14; ++j)
                acc[j] += fl[j] * wt[dy * 3] + fl[j + 1] * wt[dy * 3 + 1] + fl[j + 2] * wt[dy * 3 + 2];
        }
        #pragma unroll
        for (int j = 0; j < 14; ++j) {
            const int px = row2 * 56 + q * 14 + j;
            const float mv = mfv_[px];                         // wave-uniform
            float v = fminf(fmaxf(acc[j], 0.f), 6.f) * mv;
            h2s[px * H2STR + (((c >> 3) ^ (px & 7)) << 3) + (c & 7)] = (unsigned short)pkbf(v, v);
        }
    };

    f32x4 pacc[7];
    #pragma unroll
    for (int nt = 0; nt < 7; ++nt) {
        pacc[nt][0] = 0.f; pacc[nt][1] = 0.f; pacc[nt][2] = 0.f; pacc[nt][3] = 0.f;
    }

    auto phaseP = [&](int ch) {
        #pragma unroll
        for (int ks = 0; ks < 2; ++ks) {
            const bf16x8 pw = *(const bf16x8*)&w2f[((((wv * 12 + ch) * 2 + ks) * 64) + lane) << 3];
            #pragma unroll
            for (int nt = 0; nt < 7; ++nt) {
                const int px = nt * 16 + r16;
                const bf16x8 hb = *(const bf16x8*)&h2s[px * H2STR + (((ks * 4 + g) ^ (px & 7)) << 3)];
                pacc[nt] = __builtin_amdgcn_mfma_f32_16x16x32_bf16(pw, hb, pacc[nt], 0, 0, 0);
            }
        }
    };

    // ---- main loop: dbuf stg; stage(next) overlaps P ----
    stage(0);
    __syncthreads();
    for (int ch = 0; ch < 12; ++ch) {
        phaseDW(ch);
        __syncthreads();                      // h2s ready
        if (ch + 1 < 12) stage(ch + 1);       // fill other buffer under P
        phaseP(ch);
        __syncthreads();                      // stg ready; h2s free
    }

    // ---- epilogue: out = x + (proj + be3) * mf ----
    {
        const int ob = wv * 16 + g * 4;
        const float4 be4 = *(const float4*)&be3g[ob];
        #pragma unroll
        for (int nt = 0; nt < 7; ++nt) {
            const int px = nt * 16 + r16;
            const float mv = mfv_[px];
            const size_t base = (size_t)(b * OUP + ob) * HWSZ + p0 + px;
            out[base]            = x[base]            + (pacc[nt][0] + be4.x) * mv;
            out[base + HWSZ]     = x[base + HWSZ]     + (pacc[nt][1] + be4.y) * mv;
            out[base + 2 * HWSZ] = x[base + 2 * HWSZ] + (pacc[nt][2] + be4.z) * mv;
            out[base + 3 * HWSZ] = x[base + 3 * HWSZ] + (pacc[nt][3] + be4.w) * mv;
        }
    }
}

extern "C" void kernel_launch(void* const* d_in, const int* in_sizes, int n_in,
                              void* d_out, int out_size, void* d_ws, size_t ws_size,
                              hipStream_t stream) {
    (void)in_sizes; (void)n_in; (void)out_size; (void)ws_size;
    const float* x   = (const float*)d_in[0];
    const float* w1  = (const float*)d_in[1];
    const float* g1  = (const float*)d_in[2];
    const float* b1  = (const float*)d_in[3];
    const float* m1  = (const float*)d_in[4];
    const float* v1  = (const float*)d_in[5];
    const float* wdw = (const float*)d_in[6];
    const float* g2  = (const float*)d_in[7];
    const float* b2  = (const float*)d_in[8];
    const float* m2  = (const float*)d_in[9];
    const float* v2  = (const float*)d_in[10];
    const float* w2  = (const float*)d_in[11];
    const float* g3  = (const float*)d_in[12];
    const float* b3  = (const float*)d_in[13];
    const float* m3  = (const float*)d_in[14];
    const float* v3  = (const float*)d_in[15];
    const int*  mask = (const int*)d_in[16];
    float* out = (float*)d_out;

    char* ws = (char*)d_ws;
    unsigned short* w1f = (unsigned short*)ws;                 // 196608 B
    unsigned short* w2f = (unsigned short*)(ws + 196608);      // 196608 B
    float* be1o = (float*)(ws + 393216);                       // 3072 B
    float* wdsf = (float*)(ws + 396288);                       // 27648 B  [9][768]
    float* be2o = (float*)(ws + 423936);                       // 3072 B
    float* be3o = (float*)(ws + 427008);                       // 512 B
    float* mdf  = (float*)(ws + 427520);                       // 200704 B
    float* mff  = (float*)(ws + 628224);                       // 200704 B
    unsigned* h1p = (unsigned*)(ws + 828928);                  // 77070336 B (bf16 pairs)

    prep<<<256, 256, 0, stream>>>(w1, g1, b1, m1, v1, wdw, g2, b2, m2, v2,
                                  w2, g3, b3, m3, v3, mask,
                                  w1f, w2f, be1o, wdsf, be2o, be3o, mdf, mff);
    k1_expand<<<dim3(1200), 512, 0, stream>>>(x, w1f, be1o, mdf, h1p);
    k23<<<dim3(448), 512, 0, stream>>>(h1p, w2f, wdsf, be2o, be3o, mff, x, out);
}